// Round 21
// baseline (107.806 us; speedup 1.0000x reference)
//
#include <hip/hip_runtime.h>
#include <math.h>

#define N_TOK 2048

typedef __attribute__((ext_vector_type(8))) short short8;    // 8 bf16
typedef __attribute__((ext_vector_type(4))) float f32x4;
typedef __attribute__((ext_vector_type(16))) float f32x16;

__device__ __forceinline__ float gelu_f(float v) {
    return 0.5f * v * (1.0f + erff(v * 0.7071067811865475f));
}
__device__ __forceinline__ ushort f2bf(float x) {
    uint u = __float_as_uint(x);
    uint r = u + 0x7FFFu + ((u >> 16) & 1u);
    return (ushort)(r >> 16);
}
__device__ __forceinline__ float bf2f(ushort u) {
    return __uint_as_float((uint)u << 16);
}
// async global->LDS, 16B per lane; LDS dest = wave-uniform base + lane*16
__device__ __forceinline__ void gload16(const void* g, void* s) {
    __builtin_amdgcn_global_load_lds((const __attribute__((address_space(1))) void*)g,
                                     (__attribute__((address_space(3))) void*)s, 16, 0, 0);
}

// ---- prep: weight f32->bf16 convert (blocks 0..1279) + x transpose (1280..2303) ----
__global__ __launch_bounds__(256)
void prep(const float* __restrict__ w0, ushort* __restrict__ o0,
          const float* __restrict__ w1, ushort* __restrict__ o1,
          const float* __restrict__ w2, ushort* __restrict__ o2,
          const float* __restrict__ x, ushort* __restrict__ xt)
{
    __shared__ ushort sT[64 * 68];
    const int tid = threadIdx.x;
    int bx = blockIdx.x;
    if (bx < 1280) {
        int i4 = bx * 256 + tid;   // 327680 float4s total
        const float* src; ushort* dst; int idx;
        if (i4 < 196608)      { src = w0; dst = o0; idx = i4; }
        else if (i4 < 262144) { src = w1; dst = o1; idx = i4 - 196608; }
        else                  { src = w2; dst = o2; idx = i4 - 262144; }
        float4 v = *(const float4*)&src[idx * 4];
        ushort4 p; p.x = f2bf(v.x); p.y = f2bf(v.y); p.z = f2bf(v.z); p.w = f2bf(v.w);
        *(ushort4*)&dst[idx * 4] = p;
        return;
    }
    bx -= 1280;                                 // 1024 transpose blocks
    const int tok0 = (bx & 31) * 64;
    const int ch0 = ((bx >> 5) & 7) * 64;
    const int bi = bx >> 8;
    #pragma unroll
    for (int i = 0; i < 4; i++) {
        int ch = (tid >> 4) + i * 16;
        int t4 = (tid & 15) * 4;
        float4 v = *(const float4*)&x[((size_t)bi * 512 + ch0 + ch) * N_TOK + tok0 + t4];
        ushort4 p; p.x = f2bf(v.x); p.y = f2bf(v.y); p.z = f2bf(v.z); p.w = f2bf(v.w);
        *(ushort4*)&sT[ch * 68 + t4] = p;
    }
    __syncthreads();
    const int tr = (tid & 15) + (tid >> 6) * 16;
    const int cb = ((tid >> 4) & 3) * 16;
    uint vv[8];
    #pragma unroll
    for (int j = 0; j < 8; j++) {
        uint lo = sT[(cb + 2 * j) * 68 + tr];
        uint hi = sT[(cb + 2 * j + 1) * 68 + tr];
        vv[j] = lo | (hi << 16);
    }
    size_t base = ((size_t)bi * N_TOK + tok0 + tr) * 512 + ch0 + cb;
    *(uint4*)&xt[base]     = *(uint4*)&vv[0];
    *(uint4*)&xt[base + 8] = *(uint4*)&vv[4];
}

// ---- bf16 MFMA GEMM: C[b] = A @ Bt[b]^T ----
// 2-buffer one-barrier-per-tile pipeline + XCD-contiguous 1-D grid remap (r20).
template<int MODE, int BM, int BN>
__global__ __launch_bounds__(256)
void bgemm(const ushort* __restrict__ A, const ushort* __restrict__ Bt, int M,
           ushort* __restrict__ qt, ushort* __restrict__ vc,
           float* __restrict__ outF, ushort* __restrict__ outB,
           const float* __restrict__ bias,
           const float* __restrict__ g, const float* __restrict__ be,
           const float* __restrict__ mu, const float* __restrict__ va,
           const ushort* __restrict__ residB)
{
    constexpr int MF = BM / 32, NF = BN / 32;
    __shared__ ushort sA[2][BM * 64];
    __shared__ ushort sB[2][BN * 64];
    const int tid = threadIdx.x;
    const int w = tid >> 6, l = tid & 63;
    const int l16 = l & 15, lg = l >> 4;
    const int wr = w >> 1, wc = w & 1;
    const int NY = M / BM;
    const int nblk = 16 * NY * 4;                     // N_TOK/BN==16 for BN=128
    const int phys = blockIdx.x;
    const int logi = (phys & 7) * (nblk >> 3) + (phys >> 3);
    const int bxg = logi & 15;
    const int rest = logi >> 4;
    const int byg = rest % NY;
    const int bi = rest / NY;
    const int m0 = byg * BM, n0 = bxg * BN;
    const ushort* Bb = Bt + (size_t)bi * N_TOK * 512;
    const int srow = l >> 3, spos = l & 7;

    f32x4 acc[MF][NF];
    #pragma unroll
    for (int i = 0; i < MF; i++)
        #pragma unroll
        for (int j = 0; j < NF; j++) acc[i][j] = (f32x4){0.f, 0.f, 0.f, 0.f};

#define GSTAGE(T, BUF) \
    { \
        const int kt_ = (T) * 64; \
        _Pragma("unroll") \
        for (int i_ = 0; i_ < BM / 32; i_++) { \
            int row_ = w * (BM / 4) + i_ * 8 + srow; \
            int c_ = spos ^ (row_ & 7); \
            gload16(A + (size_t)(m0 + row_) * 512 + kt_ + c_ * 8, \
                    &sA[BUF][(w * (BM / 4) + i_ * 8) * 64]); \
        } \
        _Pragma("unroll") \
        for (int i_ = 0; i_ < BN / 32; i_++) { \
            int row_ = w * (BN / 4) + i_ * 8 + srow; \
            int c_ = spos ^ (row_ & 7); \
            gload16(Bb + (size_t)(n0 + row_) * 512 + kt_ + c_ * 8, \
                    &sB[BUF][(w * (BN / 4) + i_ * 8) * 64]); \
        } \
    }

    GSTAGE(0, 0)

    for (int t = 0; t < 8; t++) {
        asm volatile("s_waitcnt vmcnt(0)" ::: "memory");
        __builtin_amdgcn_s_barrier();
        __builtin_amdgcn_sched_barrier(0);
        if (t + 1 < 8) { GSTAGE(t + 1, (t + 1) & 1) }
        const int cur = t & 1;

        #pragma unroll
        for (int ks = 0; ks < 2; ks++) {
            short8 af[MF], bfv[NF];
            #pragma unroll
            for (int mi = 0; mi < MF; mi++) {
                int row = wr * (BM / 2) + mi * 16 + l16;
                af[mi] = *(const short8*)&sA[cur][row * 64 +
                          (((ks * 4 + lg) ^ (row & 7)) << 3)];
            }
            #pragma unroll
            for (int ni = 0; ni < NF; ni++) {
                int row = wc * (BN / 2) + ni * 16 + l16;
                bfv[ni] = *(const short8*)&sB[cur][row * 64 +
                           (((ks * 4 + lg) ^ (row & 7)) << 3)];
            }
            __builtin_amdgcn_s_setprio(1);
            #pragma unroll
            for (int mi = 0; mi < MF; mi++)
                #pragma unroll
                for (int ni = 0; ni < NF; ni++)
                    acc[mi][ni] = __builtin_amdgcn_mfma_f32_16x16x32_bf16(
                        af[mi], bfv[ni], acc[mi][ni], 0, 0, 0);
            __builtin_amdgcn_s_setprio(0);
        }
    }
#undef GSTAGE

    const int chb = m0 + wr * (BM / 2);
    const int tkb = n0 + wc * (BN / 2);
    if (MODE == 0) {
        if (m0 < 1024) {
            const float qs = (m0 < 512) ? 0.18033688f : 1.0f;   // 0.125*log2e for Q
            #pragma unroll
            for (int mi = 0; mi < MF; mi++) {
                int ob = chb + mi * 16 + lg * 4;
                #pragma unroll
                for (int ni = 0; ni < NF; ni++) {
                    int tok = tkb + ni * 16 + l16;
                    ushort4 p;
                    p.x = f2bf(acc[mi][ni][0] * qs); p.y = f2bf(acc[mi][ni][1] * qs);
                    p.z = f2bf(acc[mi][ni][2] * qs); p.w = f2bf(acc[mi][ni][3] * qs);
                    *(ushort4*)&qt[((size_t)bi * N_TOK + tok) * 1024 + ob] = p;
                }
            }
        } else {
            #pragma unroll
            for (int mi = 0; mi < MF; mi++)
                #pragma unroll
                for (int r = 0; r < 4; r++) {
                    int o = chb + mi * 16 + lg * 4 + r - 1024;
                    #pragma unroll
                    for (int ni = 0; ni < NF; ni++) {
                        int tok = tkb + ni * 16 + l16;
                        vc[((size_t)bi * 512 + o) * N_TOK + tok] = f2bf(acc[mi][ni][r]);
                    }
                }
        }
    } else {
        #pragma unroll
        for (int mi = 0; mi < MF; mi++) {
            float inv[4], sh[4], bb[4];
            #pragma unroll
            for (int r = 0; r < 4; r++) {
                int o = chb + mi * 16 + lg * 4 + r;
                inv[r] = g[o] * rsqrtf(va[o] + 1e-5f);
                sh[r]  = be[o] - mu[o] * inv[r];
                bb[r]  = (MODE == 1) ? bias[o] : 0.f;
            }
            #pragma unroll
            for (int ni = 0; ni < NF; ni++) {
                int tok = tkb + ni * 16 + l16;
                ushort4 rv = *(const ushort4*)&residB[((size_t)bi * N_TOK + tok) * 512 +
                                                      chb + mi * 16 + lg * 4];
                float rr_[4] = {bf2f(rv.x), bf2f(rv.y), bf2f(rv.z), bf2f(rv.w)};
                float ov[4];
                #pragma unroll
                for (int r = 0; r < 4; r++) {
                    float y = (acc[mi][ni][r] + bb[r]) * inv[r] + sh[r];
                    ov[r] = gelu_f((MODE == 1) ? (y + rr_[r]) : (rr_[r] + y));
                }
                if (MODE == 1) {
                    ushort4 p;
                    p.x = f2bf(ov[0]); p.y = f2bf(ov[1]);
                    p.z = f2bf(ov[2]); p.w = f2bf(ov[3]);
                    *(ushort4*)&outB[((size_t)bi * N_TOK + tok) * 512 +
                                     chb + mi * 16 + lg * 4] = p;
                } else {
                    #pragma unroll
                    for (int r = 0; r < 4; r++) {
                        int o = chb + mi * 16 + lg * 4 + r;
                        outF[((size_t)bi * 512 + o) * N_TOK + tok] = ov[r];
                    }
                }
            }
        }
    }
}

// ---- MFMA flash attention: r17 structure + 16B skew-pad LDS (bank-conflict fix) ----
// 256 blocks x 8 waves; 256 q-rows/block (32/wave), 16 KV tiles of 128.
// LDS laid out as 16 staging units of 1040B per tile (1KB data + 16B pad):
// unit index now rotates bank-quads ((u + chunk^key)&7), breaking the 4-way
// aliasing of 128B/256B row strides. Staging sources unchanged (key=row&7
// involution preserved); only dest unit bases and read addresses change.
__global__ __launch_bounds__(512)
void attn_mfma(const ushort* __restrict__ qt, const ushort* __restrict__ vc,
               ushort* __restrict__ aout)
{
    // ring slot = 16 units * 520 ushorts (1040B); 3 slots each for K and V
    __shared__ ushort sK[3 * 16 * 520];   // 49920 B
    __shared__ ushort sV[3 * 16 * 520];   // 49920 B
    const int tid = threadIdx.x;
    const int w = tid >> 6, l = tid & 63;
    const int c = l & 31, h = l >> 5;
    const int phys = blockIdx.x;                      // 256 blocks
    const int logi = (phys & 7) * 32 + (phys >> 3);   // XCD-contiguous (256%8==0)
    const int qblk = logi & 7;                        // 8 q-blocks of 256 rows
    const int pair = logi >> 3;                       // 0..31
    const int hh = pair & 7, bi = pair >> 3;
    const int qw = qblk * 256 + w * 32;
    const int srow = l >> 3, spos = l & 7;

    // K staging source (rows of 64 d-elems = 8 chunks, pre-swizzled chunk key=row&7)
    const ushort* kSrc = qt + (size_t)bi * N_TOK * 1024 + 512 + hh * 64 + ((spos ^ srow) << 3);
    // V staging sources (rows of 128 kv-elems = 16 chunks; 4 rows per gload16)
    const int vr = l >> 4, vp = l & 15;
    const ushort* vSrc0 = vc + (size_t)(bi * 512 + hh * 64 + vr) * N_TOK +
                          ((vp ^ vr) << 3);                 // rows base+0..3 (key=vr)
    const ushort* vSrc1 = vc + (size_t)(bi * 512 + hh * 64 + 4 + vr) * N_TOK +
                          ((vp ^ (4 + vr)) << 3);           // rows base+4..7 (key=4+vr)

    // per-lane read bases (skewed layout)
    const int kbase = (c >> 3) * 520 + (c & 7) * 64;    // + s*4*520 per subtile
    const int vbase = (c >> 2) * 520 + (c & 3) * 128;   // + dt*8*520 per d-half

    // Q (B-operand): lane(c,h): Q[qw+c][d = dk*16 + 8h + j]
    short8 qf[4];
    #pragma unroll
    for (int dk = 0; dk < 4; dk++)
        qf[dk] = *(const short8*)(qt +
            (size_t)(bi * N_TOK + qw + c) * 1024 + hh * 64 + dk * 16 + h * 8);

    f32x16 oacc[2];
    #pragma unroll
    for (int dt = 0; dt < 2; dt++)
        #pragma unroll
        for (int i = 0; i < 16; i++) oacc[dt][i] = 0.f;
    float lsum = 0.f;

    // stage tile T (128 kv) into ring slot BUF: per wave 2 K-units + 2 V-units.
#define STAGE(T, BUF) \
    { \
        const int kv0_ = (T) * 128; \
        ushort* kb_ = &sK[(BUF) * 8320]; \
        ushort* vb_ = &sV[(BUF) * 8320]; \
        gload16(kSrc + (size_t)(kv0_ + w * 16 + srow) * 1024,     kb_ + (w * 2) * 520); \
        gload16(kSrc + (size_t)(kv0_ + w * 16 + 8 + srow) * 1024, kb_ + (w * 2 + 1) * 520); \
        gload16(vSrc0 + (size_t)(w * 8) * N_TOK + kv0_,           vb_ + (w * 2) * 520); \
        gload16(vSrc1 + (size_t)(w * 8) * N_TOK + kv0_,           vb_ + (w * 2 + 1) * 520); \
    }

    STAGE(0, 0)
    STAGE(1, 1)

    const int NT = N_TOK / 128;         // 16
    for (int t = 0; t < NT; t++) {
        if (t < NT - 1) { asm volatile("s_waitcnt vmcnt(4)" ::: "memory"); }
        else            { asm volatile("s_waitcnt vmcnt(0)" ::: "memory"); }
        __builtin_amdgcn_s_barrier();
        __builtin_amdgcn_sched_barrier(0);
        const int b_c = t % 3;
        if (t + 2 < NT) { STAGE(t + 2, (t + 2) % 3) }

        const ushort* kB = &sK[b_c * 8320];
        const ushort* vB = &sV[b_c * 8320];

        #pragma unroll
        for (int s = 0; s < 4; s++) {          // four 32-kv subtiles per staged 128
            // ---- S^T = K Q : A=K (row=kv, k=d), B=Q (col=q, k=d) ----
            f32x16 sacc;
            #pragma unroll
            for (int i = 0; i < 16; i++) sacc[i] = 0.f;
            __builtin_amdgcn_s_setprio(1);
            #pragma unroll
            for (int dk = 0; dk < 4; dk++) {
                short8 kf = *(const short8*)&kB[s * 4 * 520 + kbase +
                             (((dk * 2 + h) ^ (c & 7)) << 3)];
                sacc = __builtin_amdgcn_mfma_f32_32x32x16_bf16(kf, qf[dk], sacc, 0, 0, 0);
            }
            __builtin_amdgcn_s_setprio(0);

            // ---- p = 2^s (m=0 safe: |s|max ~1.2); pack to bf16 pairs in-reg ----
            uint u0_0, u0_1, u1_0, u1_1, u2_0, u2_1, u3_0, u3_1;
            float ps = 0.f;
            {
                float p0, p1, p2, p3;
#define PACK_G(G, U0, U1) \
                p0 = __builtin_amdgcn_exp2f(sacc[4*G+0]); \
                p1 = __builtin_amdgcn_exp2f(sacc[4*G+1]); \
                p2 = __builtin_amdgcn_exp2f(sacc[4*G+2]); \
                p3 = __builtin_amdgcn_exp2f(sacc[4*G+3]); \
                ps += (p0 + p1) + (p2 + p3); \
                asm("v_cvt_pk_bf16_f32 %0, %1, %2" : "=v"(U0) : "v"(p0), "v"(p1)); \
                asm("v_cvt_pk_bf16_f32 %0, %1, %2" : "=v"(U1) : "v"(p2), "v"(p3));
                PACK_G(0, u0_0, u0_1)
                PACK_G(1, u1_0, u1_1)
                PACK_G(2, u2_0, u2_1)
                PACK_G(3, u3_0, u3_1)
#undef PACK_G
            }
            lsum += ps;

            // ---- PV: A-frag via permlane32_swap (zero-LDS P), B=V from LDS ----
#define PV_STEP(T2, A0, A1, B0, B1) \
            { \
                uint a0 = A0, b0 = B0, a1 = A1, b1 = B1; \
                asm volatile("v_permlane32_swap_b32 %0, %1" : "+v"(b0), "+v"(a0)); \
                asm volatile("v_permlane32_swap_b32 %0, %1" : "+v"(b1), "+v"(a1)); \
                uint4 fu = make_uint4(a0, a1, b0, b1); \
                short8 pf = *(short8*)&fu; \
                __builtin_amdgcn_s_setprio(1); \
                _Pragma("unroll") \
                for (int dt = 0; dt < 2; dt++) { \
                    short8 vf = *(const short8*)&vB[dt * 8 * 520 + vbase + \
                                 (((s * 4 + T2 * 2 + h) ^ (c & 7)) << 3)]; \
                    oacc[dt] = __builtin_amdgcn_mfma_f32_32x32x16_bf16( \
                        pf, vf, oacc[dt], 0, 0, 0); \
                } \
                __builtin_amdgcn_s_setprio(0); \
            }
            PV_STEP(0, u0_0, u0_1, u1_0, u1_1)
            PV_STEP(1, u2_0, u2_1, u3_0, u3_1)
#undef PV_STEP
        }
    }
#undef STAGE

    // ---- epilogue: q = c for every value this lane holds -> lane-local 1/l ----
    lsum += __shfl_xor(lsum, 32);
    float rl = 1.f / lsum;
    #pragma unroll
    for (int dt = 0; dt < 2; dt++)
        #pragma unroll
        for (int g = 0; g < 4; g++) {
            float o0 = oacc[dt][4 * g + 0] * rl;
            float o1 = oacc[dt][4 * g + 1] * rl;
            float o2 = oacc[dt][4 * g + 2] * rl;
            float o3 = oacc[dt][4 * g + 3] * rl;
            uint p0, p1;
            asm("v_cvt_pk_bf16_f32 %0, %1, %2" : "=v"(p0) : "v"(o0), "v"(o1));
            asm("v_cvt_pk_bf16_f32 %0, %1, %2" : "=v"(p1) : "v"(o2), "v"(o3));
            int ch = hh * 64 + dt * 32 + 8 * g + 4 * h;
            *(uint2*)&aout[((size_t)bi * N_TOK + qw + c) * 512 + ch] = make_uint2(p0, p1);
        }
}

extern "C" void kernel_launch(void* const* d_in, const int* in_sizes, int n_in,
                              void* d_out, int out_size, void* d_ws, size_t ws_size,
                              hipStream_t stream) {
    const float* x    = (const float*)d_in[0];
    const float* Wqkv = (const float*)d_in[1];
    const float* Wout = (const float*)d_in[2];
    const float* bout = (const float*)d_in[3];
    const float* g1   = (const float*)d_in[4];
    const float* be1  = (const float*)d_in[5];
    const float* m1   = (const float*)d_in[6];
    const float* v1   = (const float*)d_in[7];
    const float* Wffn = (const float*)d_in[8];
    const float* g2   = (const float*)d_in[9];
    const float* be2  = (const float*)d_in[10];
    const float* m2   = (const float*)d_in[11];
    const float* v2   = (const float*)d_in[12];

    char* ws = (char*)d_ws;
    ushort* wqB  = (ushort*)(ws + 0);          // 1.5 MB
    ushort* woB  = (ushort*)(ws + 1572864);    // 0.5 MB
    ushort* wfB  = (ushort*)(ws + 2097152);    // 0.5 MB
    ushort* xt   = (ushort*)(ws + 2621440);    // 8 MB   [b][2048][512] bf16
    ushort* qtp  = (ushort*)(ws + 11010048);   // 16 MB  [b][2048][1024] bf16
    ushort* vcp  = (ushort*)(ws + 27787264);   // 8 MB   [b][512][2048] bf16
    ushort* aout = (ushort*)(ws + 36175872);   // 8 MB   [b][2048][512] bf16
    ushort* attB = (ushort*)(ws + 27787264);   // 8 MB   reuse vcp (dead after attn)

    dim3 blk(256);
    prep<<<2304, blk, 0, stream>>>(Wqkv, wqB, Wout, woB, Wffn, wfB, x, xt);
    bgemm<0, 128, 128><<<dim3(768), blk, 0, stream>>>(
        wqB, xt, 1536, qtp, vcp, nullptr, nullptr,
        nullptr, nullptr, nullptr, nullptr, nullptr, nullptr);
    attn_mfma<<<dim3(256), dim3(512), 0, stream>>>(qtp, vcp, aout);
    bgemm<1, 64, 128><<<dim3(512), blk, 0, stream>>>(
        woB, aout, 512, nullptr, nullptr, nullptr, attB,
        bout, g1, be1, m1, v1, xt);
    bgemm<2, 64, 128><<<dim3(512), blk, 0, stream>>>(
        wfB, attB, 512, nullptr, nullptr, (float*)d_out, nullptr,
        nullptr, g2, be2, m2, v2, attB);
}

// Round 22
// 107.688 us; speedup vs baseline: 1.0011x; 1.0011x over previous
//
#include <hip/hip_runtime.h>
#include <math.h>

#define N_TOK 2048

typedef __attribute__((ext_vector_type(8))) short short8;    // 8 bf16
typedef __attribute__((ext_vector_type(4))) float f32x4;
typedef __attribute__((ext_vector_type(16))) float f32x16;

__device__ __forceinline__ float gelu_f(float v) {
    return 0.5f * v * (1.0f + erff(v * 0.7071067811865475f));
}
__device__ __forceinline__ ushort f2bf(float x) {
    uint u = __float_as_uint(x);
    uint r = u + 0x7FFFu + ((u >> 16) & 1u);
    return (ushort)(r >> 16);
}
__device__ __forceinline__ float bf2f(ushort u) {
    return __uint_as_float((uint)u << 16);
}
// async global->LDS, 16B per lane; LDS dest = wave-uniform base + lane*16
__device__ __forceinline__ void gload16(const void* g, void* s) {
    __builtin_amdgcn_global_load_lds((const __attribute__((address_space(1))) void*)g,
                                     (__attribute__((address_space(3))) void*)s, 16, 0, 0);
}

// ---- prep: weight f32->bf16 convert (blocks 0..1279) + x transpose (1280..2303) ----
__global__ __launch_bounds__(256)
void prep(const float* __restrict__ w0, ushort* __restrict__ o0,
          const float* __restrict__ w1, ushort* __restrict__ o1,
          const float* __restrict__ w2, ushort* __restrict__ o2,
          const float* __restrict__ x, ushort* __restrict__ xt)
{
    __shared__ ushort sT[64 * 68];
    const int tid = threadIdx.x;
    int bx = blockIdx.x;
    if (bx < 1280) {
        int i4 = bx * 256 + tid;   // 327680 float4s total
        const float* src; ushort* dst; int idx;
        if (i4 < 196608)      { src = w0; dst = o0; idx = i4; }
        else if (i4 < 262144) { src = w1; dst = o1; idx = i4 - 196608; }
        else                  { src = w2; dst = o2; idx = i4 - 262144; }
        float4 v = *(const float4*)&src[idx * 4];
        ushort4 p; p.x = f2bf(v.x); p.y = f2bf(v.y); p.z = f2bf(v.z); p.w = f2bf(v.w);
        *(ushort4*)&dst[idx * 4] = p;
        return;
    }
    bx -= 1280;                                 // 1024 transpose blocks
    const int tok0 = (bx & 31) * 64;
    const int ch0 = ((bx >> 5) & 7) * 64;
    const int bi = bx >> 8;
    #pragma unroll
    for (int i = 0; i < 4; i++) {
        int ch = (tid >> 4) + i * 16;
        int t4 = (tid & 15) * 4;
        float4 v = *(const float4*)&x[((size_t)bi * 512 + ch0 + ch) * N_TOK + tok0 + t4];
        ushort4 p; p.x = f2bf(v.x); p.y = f2bf(v.y); p.z = f2bf(v.z); p.w = f2bf(v.w);
        *(ushort4*)&sT[ch * 68 + t4] = p;
    }
    __syncthreads();
    const int tr = (tid & 15) + (tid >> 6) * 16;
    const int cb = ((tid >> 4) & 3) * 16;
    uint vv[8];
    #pragma unroll
    for (int j = 0; j < 8; j++) {
        uint lo = sT[(cb + 2 * j) * 68 + tr];
        uint hi = sT[(cb + 2 * j + 1) * 68 + tr];
        vv[j] = lo | (hi << 16);
    }
    size_t base = ((size_t)bi * N_TOK + tok0 + tr) * 512 + ch0 + cb;
    *(uint4*)&xt[base]     = *(uint4*)&vv[0];
    *(uint4*)&xt[base + 8] = *(uint4*)&vv[4];
}

// ---- bf16 MFMA GEMM: C[b] = A @ Bt[b]^T ----
// 2-buffer one-barrier-per-tile pipeline + XCD-contiguous 1-D grid remap (r20).
template<int MODE, int BM, int BN>
__global__ __launch_bounds__(256)
void bgemm(const ushort* __restrict__ A, const ushort* __restrict__ Bt, int M,
           ushort* __restrict__ qt, ushort* __restrict__ vc,
           float* __restrict__ outF, ushort* __restrict__ outB,
           const float* __restrict__ bias,
           const float* __restrict__ g, const float* __restrict__ be,
           const float* __restrict__ mu, const float* __restrict__ va,
           const ushort* __restrict__ residB)
{
    constexpr int MF = BM / 32, NF = BN / 32;
    __shared__ ushort sA[2][BM * 64];
    __shared__ ushort sB[2][BN * 64];
    const int tid = threadIdx.x;
    const int w = tid >> 6, l = tid & 63;
    const int l16 = l & 15, lg = l >> 4;
    const int wr = w >> 1, wc = w & 1;
    const int NY = M / BM;
    const int nblk = 16 * NY * 4;                     // N_TOK/BN==16 for BN=128
    const int phys = blockIdx.x;
    const int logi = (phys & 7) * (nblk >> 3) + (phys >> 3);
    const int bxg = logi & 15;
    const int rest = logi >> 4;
    const int byg = rest % NY;
    const int bi = rest / NY;
    const int m0 = byg * BM, n0 = bxg * BN;
    const ushort* Bb = Bt + (size_t)bi * N_TOK * 512;
    const int srow = l >> 3, spos = l & 7;

    f32x4 acc[MF][NF];
    #pragma unroll
    for (int i = 0; i < MF; i++)
        #pragma unroll
        for (int j = 0; j < NF; j++) acc[i][j] = (f32x4){0.f, 0.f, 0.f, 0.f};

#define GSTAGE(T, BUF) \
    { \
        const int kt_ = (T) * 64; \
        _Pragma("unroll") \
        for (int i_ = 0; i_ < BM / 32; i_++) { \
            int row_ = w * (BM / 4) + i_ * 8 + srow; \
            int c_ = spos ^ (row_ & 7); \
            gload16(A + (size_t)(m0 + row_) * 512 + kt_ + c_ * 8, \
                    &sA[BUF][(w * (BM / 4) + i_ * 8) * 64]); \
        } \
        _Pragma("unroll") \
        for (int i_ = 0; i_ < BN / 32; i_++) { \
            int row_ = w * (BN / 4) + i_ * 8 + srow; \
            int c_ = spos ^ (row_ & 7); \
            gload16(Bb + (size_t)(n0 + row_) * 512 + kt_ + c_ * 8, \
                    &sB[BUF][(w * (BN / 4) + i_ * 8) * 64]); \
        } \
    }

    GSTAGE(0, 0)

    for (int t = 0; t < 8; t++) {
        asm volatile("s_waitcnt vmcnt(0)" ::: "memory");
        __builtin_amdgcn_s_barrier();
        __builtin_amdgcn_sched_barrier(0);
        if (t + 1 < 8) { GSTAGE(t + 1, (t + 1) & 1) }
        const int cur = t & 1;

        #pragma unroll
        for (int ks = 0; ks < 2; ks++) {
            short8 af[MF], bfv[NF];
            #pragma unroll
            for (int mi = 0; mi < MF; mi++) {
                int row = wr * (BM / 2) + mi * 16 + l16;
                af[mi] = *(const short8*)&sA[cur][row * 64 +
                          (((ks * 4 + lg) ^ (row & 7)) << 3)];
            }
            #pragma unroll
            for (int ni = 0; ni < NF; ni++) {
                int row = wc * (BN / 2) + ni * 16 + l16;
                bfv[ni] = *(const short8*)&sB[cur][row * 64 +
                           (((ks * 4 + lg) ^ (row & 7)) << 3)];
            }
            __builtin_amdgcn_s_setprio(1);
            #pragma unroll
            for (int mi = 0; mi < MF; mi++)
                #pragma unroll
                for (int ni = 0; ni < NF; ni++)
                    acc[mi][ni] = __builtin_amdgcn_mfma_f32_16x16x32_bf16(
                        af[mi], bfv[ni], acc[mi][ni], 0, 0, 0);
            __builtin_amdgcn_s_setprio(0);
        }
    }
#undef GSTAGE

    const int chb = m0 + wr * (BM / 2);
    const int tkb = n0 + wc * (BN / 2);
    if (MODE == 0) {
        if (m0 < 1024) {
            const float qs = (m0 < 512) ? 0.18033688f : 1.0f;   // 0.125*log2e for Q
            #pragma unroll
            for (int mi = 0; mi < MF; mi++) {
                int ob = chb + mi * 16 + lg * 4;
                #pragma unroll
                for (int ni = 0; ni < NF; ni++) {
                    int tok = tkb + ni * 16 + l16;
                    ushort4 p;
                    p.x = f2bf(acc[mi][ni][0] * qs); p.y = f2bf(acc[mi][ni][1] * qs);
                    p.z = f2bf(acc[mi][ni][2] * qs); p.w = f2bf(acc[mi][ni][3] * qs);
                    *(ushort4*)&qt[((size_t)bi * N_TOK + tok) * 1024 + ob] = p;
                }
            }
        } else {
            #pragma unroll
            for (int mi = 0; mi < MF; mi++)
                #pragma unroll
                for (int r = 0; r < 4; r++) {
                    int o = chb + mi * 16 + lg * 4 + r - 1024;
                    #pragma unroll
                    for (int ni = 0; ni < NF; ni++) {
                        int tok = tkb + ni * 16 + l16;
                        vc[((size_t)bi * 512 + o) * N_TOK + tok] = f2bf(acc[mi][ni][r]);
                    }
                }
        }
    } else {
        #pragma unroll
        for (int mi = 0; mi < MF; mi++) {
            float inv[4], sh[4], bb[4];
            #pragma unroll
            for (int r = 0; r < 4; r++) {
                int o = chb + mi * 16 + lg * 4 + r;
                inv[r] = g[o] * rsqrtf(va[o] + 1e-5f);
                sh[r]  = be[o] - mu[o] * inv[r];
                bb[r]  = (MODE == 1) ? bias[o] : 0.f;
            }
            #pragma unroll
            for (int ni = 0; ni < NF; ni++) {
                int tok = tkb + ni * 16 + l16;
                ushort4 rv = *(const ushort4*)&residB[((size_t)bi * N_TOK + tok) * 512 +
                                                      chb + mi * 16 + lg * 4];
                float rr_[4] = {bf2f(rv.x), bf2f(rv.y), bf2f(rv.z), bf2f(rv.w)};
                float ov[4];
                #pragma unroll
                for (int r = 0; r < 4; r++) {
                    float y = (acc[mi][ni][r] + bb[r]) * inv[r] + sh[r];
                    ov[r] = gelu_f((MODE == 1) ? (y + rr_[r]) : (rr_[r] + y));
                }
                if (MODE == 1) {
                    ushort4 p;
                    p.x = f2bf(ov[0]); p.y = f2bf(ov[1]);
                    p.z = f2bf(ov[2]); p.w = f2bf(ov[3]);
                    *(ushort4*)&outB[((size_t)bi * N_TOK + tok) * 512 +
                                     chb + mi * 16 + lg * 4] = p;
                } else {
                    #pragma unroll
                    for (int r = 0; r < 4; r++) {
                        int o = chb + mi * 16 + lg * 4 + r;
                        outF[((size_t)bi * 512 + o) * N_TOK + tok] = ov[r];
                    }
                }
            }
        }
    }
}

// ---- MFMA flash attention: 8-wave blocks, KVBLK=128, counted-vmcnt 3-ring ----
// (r17/r20 version verbatim — best measured: ~51 us)
__global__ __launch_bounds__(512)
void attn_mfma(const ushort* __restrict__ qt, const ushort* __restrict__ vc,
               ushort* __restrict__ aout)
{
    __shared__ ushort sK[3][128 * 64];   // [ring][tok][d]   48KB
    __shared__ ushort sV[3][64 * 128];   // [ring][d][kv]    48KB
    const int tid = threadIdx.x;
    const int w = tid >> 6, l = tid & 63;
    const int c = l & 31, h = l >> 5;
    const int phys = blockIdx.x;                      // 256 blocks
    const int logi = (phys & 7) * 32 + (phys >> 3);   // XCD-contiguous (256%8==0)
    const int qblk = logi & 7;                        // 8 q-blocks of 256 rows
    const int pair = logi >> 3;                       // 0..31
    const int hh = pair & 7, bi = pair >> 3;
    const int qw = qblk * 256 + w * 32;
    const int srow = l >> 3, spos = l & 7;

    // K staging source (rows of 64 d-elems = 8 chunks, pre-swizzled chunk)
    const ushort* kSrc = qt + (size_t)bi * N_TOK * 1024 + 512 + hh * 64 + ((spos ^ srow) << 3);
    // V staging sources (rows of 128 kv-elems = 16 chunks; 4 rows per gload16)
    const int vr = l >> 4, vp = l & 15;
    const ushort* vSrc0 = vc + (size_t)(bi * 512 + hh * 64 + vr) * N_TOK +
                          ((vp ^ vr) << 3);                 // rows base+0..3
    const ushort* vSrc1 = vc + (size_t)(bi * 512 + hh * 64 + 4 + vr) * N_TOK +
                          ((vp ^ (4 + vr)) << 3);           // rows base+4..7

    // Q (B-operand): lane(c,h): Q[qw+c][d = dk*16 + 8h + j]
    short8 qf[4];
    #pragma unroll
    for (int dk = 0; dk < 4; dk++)
        qf[dk] = *(const short8*)(qt +
            (size_t)(bi * N_TOK + qw + c) * 1024 + hh * 64 + dk * 16 + h * 8);

    f32x16 oacc[2];
    #pragma unroll
    for (int dt = 0; dt < 2; dt++)
        #pragma unroll
        for (int i = 0; i < 16; i++) oacc[dt][i] = 0.f;
    float lsum = 0.f;

    // stage tile T (128 kv) into ring slot BUF: per wave 2 K-loads + 2 V-loads.
#define STAGE(T, BUF) \
    { \
        const int kv0_ = (T) * 128; \
        gload16(kSrc + (size_t)(kv0_ + w * 16 + srow) * 1024,     &sK[BUF][(w * 16) * 64]); \
        gload16(kSrc + (size_t)(kv0_ + w * 16 + 8 + srow) * 1024, &sK[BUF][(w * 16 + 8) * 64]); \
        gload16(vSrc0 + (size_t)(w * 8) * N_TOK + kv0_,           &sV[BUF][(w * 8) * 128]); \
        gload16(vSrc1 + (size_t)(w * 8) * N_TOK + kv0_,           &sV[BUF][(w * 8 + 4) * 128]); \
    }

    STAGE(0, 0)
    STAGE(1, 1)

    const int NT = N_TOK / 128;         // 16
    for (int t = 0; t < NT; t++) {
        if (t < NT - 1) { asm volatile("s_waitcnt vmcnt(4)" ::: "memory"); }
        else            { asm volatile("s_waitcnt vmcnt(0)" ::: "memory"); }
        __builtin_amdgcn_s_barrier();
        __builtin_amdgcn_sched_barrier(0);
        const int b_c = t % 3;
        if (t + 2 < NT) { STAGE(t + 2, (t + 2) % 3) }

        const ushort* kB = &sK[b_c][0];
        const ushort* vB = &sV[b_c][0];

        #pragma unroll
        for (int s = 0; s < 4; s++) {          // four 32-kv subtiles per staged 128
            // ---- S^T = K Q : A=K (row=kv, k=d), B=Q (col=q, k=d) ----
            f32x16 sacc;
            #pragma unroll
            for (int i = 0; i < 16; i++) sacc[i] = 0.f;
            __builtin_amdgcn_s_setprio(1);
            #pragma unroll
            for (int dk = 0; dk < 4; dk++) {
                int row = s * 32 + c;
                short8 kf = *(const short8*)&kB[row * 64 +
                             (((dk * 2 + h) ^ (row & 7)) << 3)];
                sacc = __builtin_amdgcn_mfma_f32_32x32x16_bf16(kf, qf[dk], sacc, 0, 0, 0);
            }
            __builtin_amdgcn_s_setprio(0);

            // ---- p = 2^s (m=0 safe: |s|max ~1.2); pack to bf16 pairs in-reg ----
            uint u0_0, u0_1, u1_0, u1_1, u2_0, u2_1, u3_0, u3_1;
            float ps = 0.f;
            {
                float p0, p1, p2, p3;
#define PACK_G(G, U0, U1) \
                p0 = __builtin_amdgcn_exp2f(sacc[4*G+0]); \
                p1 = __builtin_amdgcn_exp2f(sacc[4*G+1]); \
                p2 = __builtin_amdgcn_exp2f(sacc[4*G+2]); \
                p3 = __builtin_amdgcn_exp2f(sacc[4*G+3]); \
                ps += (p0 + p1) + (p2 + p3); \
                asm("v_cvt_pk_bf16_f32 %0, %1, %2" : "=v"(U0) : "v"(p0), "v"(p1)); \
                asm("v_cvt_pk_bf16_f32 %0, %1, %2" : "=v"(U1) : "v"(p2), "v"(p3));
                PACK_G(0, u0_0, u0_1)
                PACK_G(1, u1_0, u1_1)
                PACK_G(2, u2_0, u2_1)
                PACK_G(3, u3_0, u3_1)
#undef PACK_G
            }
            lsum += ps;

            // ---- PV: A-frag via permlane32_swap (zero-LDS P), B=V from LDS ----
#define PV_STEP(T2, A0, A1, B0, B1) \
            { \
                uint a0 = A0, b0 = B0, a1 = A1, b1 = B1; \
                asm volatile("v_permlane32_swap_b32 %0, %1" : "+v"(b0), "+v"(a0)); \
                asm volatile("v_permlane32_swap_b32 %0, %1" : "+v"(b1), "+v"(a1)); \
                uint4 fu = make_uint4(a0, a1, b0, b1); \
                short8 pf = *(short8*)&fu; \
                __builtin_amdgcn_s_setprio(1); \
                _Pragma("unroll") \
                for (int dt = 0; dt < 2; dt++) { \
                    int row = dt * 32 + c; \
                    short8 vf = *(const short8*)&vB[row * 128 + \
                                 (((s * 4 + T2 * 2 + h) ^ (row & 7)) << 3)]; \
                    oacc[dt] = __builtin_amdgcn_mfma_f32_32x32x16_bf16( \
                        pf, vf, oacc[dt], 0, 0, 0); \
                } \
                __builtin_amdgcn_s_setprio(0); \
            }
            PV_STEP(0, u0_0, u0_1, u1_0, u1_1)
            PV_STEP(1, u2_0, u2_1, u3_0, u3_1)
#undef PV_STEP
        }
    }
#undef STAGE

    // ---- epilogue: q = c for every value this lane holds -> lane-local 1/l ----
    lsum += __shfl_xor(lsum, 32);
    float rl = 1.f / lsum;
    #pragma unroll
    for (int dt = 0; dt < 2; dt++)
        #pragma unroll
        for (int g = 0; g < 4; g++) {
            float o0 = oacc[dt][4 * g + 0] * rl;
            float o1 = oacc[dt][4 * g + 1] * rl;
            float o2 = oacc[dt][4 * g + 2] * rl;
            float o3 = oacc[dt][4 * g + 3] * rl;
            uint p0, p1;
            asm("v_cvt_pk_bf16_f32 %0, %1, %2" : "=v"(p0) : "v"(o0), "v"(o1));
            asm("v_cvt_pk_bf16_f32 %0, %1, %2" : "=v"(p1) : "v"(o2), "v"(o3));
            int ch = hh * 64 + dt * 32 + 8 * g + 4 * h;
            *(uint2*)&aout[((size_t)bi * N_TOK + qw + c) * 512 + ch] = make_uint2(p0, p1);
        }
}

extern "C" void kernel_launch(void* const* d_in, const int* in_sizes, int n_in,
                              void* d_out, int out_size, void* d_ws, size_t ws_size,
                              hipStream_t stream) {
    const float* x    = (const float*)d_in[0];
    const float* Wqkv = (const float*)d_in[1];
    const float* Wout = (const float*)d_in[2];
    const float* bout = (const float*)d_in[3];
    const float* g1   = (const float*)d_in[4];
    const float* be1  = (const float*)d_in[5];
    const float* m1   = (const float*)d_in[6];
    const float* v1   = (const float*)d_in[7];
    const float* Wffn = (const float*)d_in[8];
    const float* g2   = (const float*)d_in[9];
    const float* be2  = (const float*)d_in[10];
    const float* m2   = (const float*)d_in[11];
    const float* v2   = (const float*)d_in[12];

    char* ws = (char*)d_ws;
    ushort* wqB  = (ushort*)(ws + 0);          // 1.5 MB
    ushort* woB  = (ushort*)(ws + 1572864);    // 0.5 MB
    ushort* wfB  = (ushort*)(ws + 2097152);    // 0.5 MB
    ushort* xt   = (ushort*)(ws + 2621440);    // 8 MB   [b][2048][512] bf16
    ushort* qtp  = (ushort*)(ws + 11010048);   // 16 MB  [b][2048][1024] bf16
    ushort* vcp  = (ushort*)(ws + 27787264);   // 8 MB   [b][512][2048] bf16
    ushort* aout = (ushort*)(ws + 36175872);   // 8 MB   [b][2048][512] bf16
    ushort* attB = (ushort*)(ws + 27787264);   // 8 MB   reuse vcp (dead after attn)

    dim3 blk(256);
    prep<<<2304, blk, 0, stream>>>(Wqkv, wqB, Wout, woB, Wffn, wfB, x, xt);
    bgemm<0, 128, 128><<<dim3(768), blk, 0, stream>>>(
        wqB, xt, 1536, qtp, vcp, nullptr, nullptr,
        nullptr, nullptr, nullptr, nullptr, nullptr, nullptr);
    attn_mfma<<<dim3(256), dim3(512), 0, stream>>>(qtp, vcp, aout);
    bgemm<1, 64, 128><<<dim3(512), blk, 0, stream>>>(
        woB, aout, 512, nullptr, nullptr, nullptr, attB,
        bout, g1, be1, m1, v1, xt);
    bgemm<2, 64, 128><<<dim3(512), blk, 0, stream>>>(
        wfB, attB, 512, nullptr, nullptr, (float*)d_out, nullptr,
        nullptr, g2, be2, m2, v2, attB);
}

// Round 23
// 107.621 us; speedup vs baseline: 1.0017x; 1.0006x over previous
//
#include <hip/hip_runtime.h>
#include <math.h>

#define N_TOK 2048

typedef __attribute__((ext_vector_type(8))) short short8;    // 8 bf16
typedef __attribute__((ext_vector_type(4))) float f32x4;
typedef __attribute__((ext_vector_type(16))) float f32x16;

__device__ __forceinline__ float gelu_f(float v) {
    return 0.5f * v * (1.0f + erff(v * 0.7071067811865475f));
}
__device__ __forceinline__ ushort f2bf(float x) {
    uint u = __float_as_uint(x);
    uint r = u + 0x7FFFu + ((u >> 16) & 1u);
    return (ushort)(r >> 16);
}
__device__ __forceinline__ float bf2f(ushort u) {
    return __uint_as_float((uint)u << 16);
}
// async global->LDS, 16B per lane; LDS dest = wave-uniform base + lane*16
__device__ __forceinline__ void gload16(const void* g, void* s) {
    __builtin_amdgcn_global_load_lds((const __attribute__((address_space(1))) void*)g,
                                     (__attribute__((address_space(3))) void*)s, 16, 0, 0);
}

// ---- prep: weight f32->bf16 convert (blocks 0..1279) + x transpose (1280..2303) ----
__global__ __launch_bounds__(256)
void prep(const float* __restrict__ w0, ushort* __restrict__ o0,
          const float* __restrict__ w1, ushort* __restrict__ o1,
          const float* __restrict__ w2, ushort* __restrict__ o2,
          const float* __restrict__ x, ushort* __restrict__ xt)
{
    __shared__ ushort sT[64 * 68];
    const int tid = threadIdx.x;
    int bx = blockIdx.x;
    if (bx < 1280) {
        int i4 = bx * 256 + tid;   // 327680 float4s total
        const float* src; ushort* dst; int idx;
        if (i4 < 196608)      { src = w0; dst = o0; idx = i4; }
        else if (i4 < 262144) { src = w1; dst = o1; idx = i4 - 196608; }
        else                  { src = w2; dst = o2; idx = i4 - 262144; }
        float4 v = *(const float4*)&src[idx * 4];
        ushort4 p; p.x = f2bf(v.x); p.y = f2bf(v.y); p.z = f2bf(v.z); p.w = f2bf(v.w);
        *(ushort4*)&dst[idx * 4] = p;
        return;
    }
    bx -= 1280;                                 // 1024 transpose blocks
    const int tok0 = (bx & 31) * 64;
    const int ch0 = ((bx >> 5) & 7) * 64;
    const int bi = bx >> 8;
    #pragma unroll
    for (int i = 0; i < 4; i++) {
        int ch = (tid >> 4) + i * 16;
        int t4 = (tid & 15) * 4;
        float4 v = *(const float4*)&x[((size_t)bi * 512 + ch0 + ch) * N_TOK + tok0 + t4];
        ushort4 p; p.x = f2bf(v.x); p.y = f2bf(v.y); p.z = f2bf(v.z); p.w = f2bf(v.w);
        *(ushort4*)&sT[ch * 68 + t4] = p;
    }
    __syncthreads();
    const int tr = (tid & 15) + (tid >> 6) * 16;
    const int cb = ((tid >> 4) & 3) * 16;
    uint vv[8];
    #pragma unroll
    for (int j = 0; j < 8; j++) {
        uint lo = sT[(cb + 2 * j) * 68 + tr];
        uint hi = sT[(cb + 2 * j + 1) * 68 + tr];
        vv[j] = lo | (hi << 16);
    }
    size_t base = ((size_t)bi * N_TOK + tok0 + tr) * 512 + ch0 + cb;
    *(uint4*)&xt[base]     = *(uint4*)&vv[0];
    *(uint4*)&xt[base + 8] = *(uint4*)&vv[4];
}

// ---- bf16 MFMA GEMM: C[b] = A @ Bt[b]^T ----
// 2-buffer one-barrier-per-tile pipeline + XCD-contiguous 1-D grid remap (r20).
template<int MODE, int BM, int BN>
__global__ __launch_bounds__(256)
void bgemm(const ushort* __restrict__ A, const ushort* __restrict__ Bt, int M,
           ushort* __restrict__ qt, ushort* __restrict__ vc,
           float* __restrict__ outF, ushort* __restrict__ outB,
           const float* __restrict__ bias,
           const float* __restrict__ g, const float* __restrict__ be,
           const float* __restrict__ mu, const float* __restrict__ va,
           const ushort* __restrict__ residB)
{
    constexpr int MF = BM / 32, NF = BN / 32;
    __shared__ ushort sA[2][BM * 64];
    __shared__ ushort sB[2][BN * 64];
    const int tid = threadIdx.x;
    const int w = tid >> 6, l = tid & 63;
    const int l16 = l & 15, lg = l >> 4;
    const int wr = w >> 1, wc = w & 1;
    const int NY = M / BM;
    const int nblk = 16 * NY * 4;                     // N_TOK/BN==16 for BN=128
    const int phys = blockIdx.x;
    const int logi = (phys & 7) * (nblk >> 3) + (phys >> 3);
    const int bxg = logi & 15;
    const int rest = logi >> 4;
    const int byg = rest % NY;
    const int bi = rest / NY;
    const int m0 = byg * BM, n0 = bxg * BN;
    const ushort* Bb = Bt + (size_t)bi * N_TOK * 512;
    const int srow = l >> 3, spos = l & 7;

    f32x4 acc[MF][NF];
    #pragma unroll
    for (int i = 0; i < MF; i++)
        #pragma unroll
        for (int j = 0; j < NF; j++) acc[i][j] = (f32x4){0.f, 0.f, 0.f, 0.f};

#define GSTAGE(T, BUF) \
    { \
        const int kt_ = (T) * 64; \
        _Pragma("unroll") \
        for (int i_ = 0; i_ < BM / 32; i_++) { \
            int row_ = w * (BM / 4) + i_ * 8 + srow; \
            int c_ = spos ^ (row_ & 7); \
            gload16(A + (size_t)(m0 + row_) * 512 + kt_ + c_ * 8, \
                    &sA[BUF][(w * (BM / 4) + i_ * 8) * 64]); \
        } \
        _Pragma("unroll") \
        for (int i_ = 0; i_ < BN / 32; i_++) { \
            int row_ = w * (BN / 4) + i_ * 8 + srow; \
            int c_ = spos ^ (row_ & 7); \
            gload16(Bb + (size_t)(n0 + row_) * 512 + kt_ + c_ * 8, \
                    &sB[BUF][(w * (BN / 4) + i_ * 8) * 64]); \
        } \
    }

    GSTAGE(0, 0)

    for (int t = 0; t < 8; t++) {
        asm volatile("s_waitcnt vmcnt(0)" ::: "memory");
        __builtin_amdgcn_s_barrier();
        __builtin_amdgcn_sched_barrier(0);
        if (t + 1 < 8) { GSTAGE(t + 1, (t + 1) & 1) }
        const int cur = t & 1;

        #pragma unroll
        for (int ks = 0; ks < 2; ks++) {
            short8 af[MF], bfv[NF];
            #pragma unroll
            for (int mi = 0; mi < MF; mi++) {
                int row = wr * (BM / 2) + mi * 16 + l16;
                af[mi] = *(const short8*)&sA[cur][row * 64 +
                          (((ks * 4 + lg) ^ (row & 7)) << 3)];
            }
            #pragma unroll
            for (int ni = 0; ni < NF; ni++) {
                int row = wc * (BN / 2) + ni * 16 + l16;
                bfv[ni] = *(const short8*)&sB[cur][row * 64 +
                           (((ks * 4 + lg) ^ (row & 7)) << 3)];
            }
            __builtin_amdgcn_s_setprio(1);
            #pragma unroll
            for (int mi = 0; mi < MF; mi++)
                #pragma unroll
                for (int ni = 0; ni < NF; ni++)
                    acc[mi][ni] = __builtin_amdgcn_mfma_f32_16x16x32_bf16(
                        af[mi], bfv[ni], acc[mi][ni], 0, 0, 0);
            __builtin_amdgcn_s_setprio(0);
        }
    }
#undef GSTAGE

    const int chb = m0 + wr * (BM / 2);
    const int tkb = n0 + wc * (BN / 2);
    if (MODE == 0) {
        if (m0 < 1024) {
            const float qs = (m0 < 512) ? 0.18033688f : 1.0f;   // 0.125*log2e for Q
            #pragma unroll
            for (int mi = 0; mi < MF; mi++) {
                int ob = chb + mi * 16 + lg * 4;
                #pragma unroll
                for (int ni = 0; ni < NF; ni++) {
                    int tok = tkb + ni * 16 + l16;
                    ushort4 p;
                    p.x = f2bf(acc[mi][ni][0] * qs); p.y = f2bf(acc[mi][ni][1] * qs);
                    p.z = f2bf(acc[mi][ni][2] * qs); p.w = f2bf(acc[mi][ni][3] * qs);
                    *(ushort4*)&qt[((size_t)bi * N_TOK + tok) * 1024 + ob] = p;
                }
            }
        } else {
            #pragma unroll
            for (int mi = 0; mi < MF; mi++)
                #pragma unroll
                for (int r = 0; r < 4; r++) {
                    int o = chb + mi * 16 + lg * 4 + r - 1024;
                    #pragma unroll
                    for (int ni = 0; ni < NF; ni++) {
                        int tok = tkb + ni * 16 + l16;
                        vc[((size_t)bi * 512 + o) * N_TOK + tok] = f2bf(acc[mi][ni][r]);
                    }
                }
        }
    } else {
        #pragma unroll
        for (int mi = 0; mi < MF; mi++) {
            float inv[4], sh[4], bb[4];
            #pragma unroll
            for (int r = 0; r < 4; r++) {
                int o = chb + mi * 16 + lg * 4 + r;
                inv[r] = g[o] * rsqrtf(va[o] + 1e-5f);
                sh[r]  = be[o] - mu[o] * inv[r];
                bb[r]  = (MODE == 1) ? bias[o] : 0.f;
            }
            #pragma unroll
            for (int ni = 0; ni < NF; ni++) {
                int tok = tkb + ni * 16 + l16;
                ushort4 rv = *(const ushort4*)&residB[((size_t)bi * N_TOK + tok) * 512 +
                                                      chb + mi * 16 + lg * 4];
                float rr_[4] = {bf2f(rv.x), bf2f(rv.y), bf2f(rv.z), bf2f(rv.w)};
                float ov[4];
                #pragma unroll
                for (int r = 0; r < 4; r++) {
                    float y = (acc[mi][ni][r] + bb[r]) * inv[r] + sh[r];
                    ov[r] = gelu_f((MODE == 1) ? (y + rr_[r]) : (rr_[r] + y));
                }
                if (MODE == 1) {
                    ushort4 p;
                    p.x = f2bf(ov[0]); p.y = f2bf(ov[1]);
                    p.z = f2bf(ov[2]); p.w = f2bf(ov[3]);
                    *(ushort4*)&outB[((size_t)bi * N_TOK + tok) * 512 +
                                     chb + mi * 16 + lg * 4] = p;
                } else {
                    #pragma unroll
                    for (int r = 0; r < 4; r++) {
                        int o = chb + mi * 16 + lg * 4 + r;
                        outF[((size_t)bi * 512 + o) * N_TOK + tok] = ov[r];
                    }
                }
            }
        }
    }
}

// ---- MFMA flash attention: 8-wave blocks, KVBLK=128, counted-vmcnt 3-ring ----
// (r17/r20 version verbatim — best measured: ~51-53 us)
__global__ __launch_bounds__(512)
void attn_mfma(const ushort* __restrict__ qt, const ushort* __restrict__ vc,
               ushort* __restrict__ aout)
{
    __shared__ ushort sK[3][128 * 64];   // [ring][tok][d]   48KB
    __shared__ ushort sV[3][64 * 128];   // [ring][d][kv]    48KB
    const int tid = threadIdx.x;
    const int w = tid >> 6, l = tid & 63;
    const int c = l & 31, h = l >> 5;
    const int phys = blockIdx.x;                      // 256 blocks
    const int logi = (phys & 7) * 32 + (phys >> 3);   // XCD-contiguous (256%8==0)
    const int qblk = logi & 7;                        // 8 q-blocks of 256 rows
    const int pair = logi >> 3;                       // 0..31
    const int hh = pair & 7, bi = pair >> 3;
    const int qw = qblk * 256 + w * 32;
    const int srow = l >> 3, spos = l & 7;

    // K staging source (rows of 64 d-elems = 8 chunks, pre-swizzled chunk)
    const ushort* kSrc = qt + (size_t)bi * N_TOK * 1024 + 512 + hh * 64 + ((spos ^ srow) << 3);
    // V staging sources (rows of 128 kv-elems = 16 chunks; 4 rows per gload16)
    const int vr = l >> 4, vp = l & 15;
    const ushort* vSrc0 = vc + (size_t)(bi * 512 + hh * 64 + vr) * N_TOK +
                          ((vp ^ vr) << 3);                 // rows base+0..3
    const ushort* vSrc1 = vc + (size_t)(bi * 512 + hh * 64 + 4 + vr) * N_TOK +
                          ((vp ^ (4 + vr)) << 3);           // rows base+4..7

    // Q (B-operand): lane(c,h): Q[qw+c][d = dk*16 + 8h + j]
    short8 qf[4];
    #pragma unroll
    for (int dk = 0; dk < 4; dk++)
        qf[dk] = *(const short8*)(qt +
            (size_t)(bi * N_TOK + qw + c) * 1024 + hh * 64 + dk * 16 + h * 8);

    f32x16 oacc[2];
    #pragma unroll
    for (int dt = 0; dt < 2; dt++)
        #pragma unroll
        for (int i = 0; i < 16; i++) oacc[dt][i] = 0.f;
    float lsum = 0.f;

    // stage tile T (128 kv) into ring slot BUF: per wave 2 K-loads + 2 V-loads.
#define STAGE(T, BUF) \
    { \
        const int kv0_ = (T) * 128; \
        gload16(kSrc + (size_t)(kv0_ + w * 16 + srow) * 1024,     &sK[BUF][(w * 16) * 64]); \
        gload16(kSrc + (size_t)(kv0_ + w * 16 + 8 + srow) * 1024, &sK[BUF][(w * 16 + 8) * 64]); \
        gload16(vSrc0 + (size_t)(w * 8) * N_TOK + kv0_,           &sV[BUF][(w * 8) * 128]); \
        gload16(vSrc1 + (size_t)(w * 8) * N_TOK + kv0_,           &sV[BUF][(w * 8 + 4) * 128]); \
    }

    STAGE(0, 0)
    STAGE(1, 1)

    const int NT = N_TOK / 128;         // 16
    for (int t = 0; t < NT; t++) {
        if (t < NT - 1) { asm volatile("s_waitcnt vmcnt(4)" ::: "memory"); }
        else            { asm volatile("s_waitcnt vmcnt(0)" ::: "memory"); }
        __builtin_amdgcn_s_barrier();
        __builtin_amdgcn_sched_barrier(0);
        const int b_c = t % 3;
        if (t + 2 < NT) { STAGE(t + 2, (t + 2) % 3) }

        const ushort* kB = &sK[b_c][0];
        const ushort* vB = &sV[b_c][0];

        #pragma unroll
        for (int s = 0; s < 4; s++) {          // four 32-kv subtiles per staged 128
            // ---- S^T = K Q : A=K (row=kv, k=d), B=Q (col=q, k=d) ----
            f32x16 sacc;
            #pragma unroll
            for (int i = 0; i < 16; i++) sacc[i] = 0.f;
            __builtin_amdgcn_s_setprio(1);
            #pragma unroll
            for (int dk = 0; dk < 4; dk++) {
                int row = s * 32 + c;
                short8 kf = *(const short8*)&kB[row * 64 +
                             (((dk * 2 + h) ^ (row & 7)) << 3)];
                sacc = __builtin_amdgcn_mfma_f32_32x32x16_bf16(kf, qf[dk], sacc, 0, 0, 0);
            }
            __builtin_amdgcn_s_setprio(0);

            // ---- p = 2^s (m=0 safe: |s|max ~1.2); pack to bf16 pairs in-reg ----
            uint u0_0, u0_1, u1_0, u1_1, u2_0, u2_1, u3_0, u3_1;
            float ps = 0.f;
            {
                float p0, p1, p2, p3;
#define PACK_G(G, U0, U1) \
                p0 = __builtin_amdgcn_exp2f(sacc[4*G+0]); \
                p1 = __builtin_amdgcn_exp2f(sacc[4*G+1]); \
                p2 = __builtin_amdgcn_exp2f(sacc[4*G+2]); \
                p3 = __builtin_amdgcn_exp2f(sacc[4*G+3]); \
                ps += (p0 + p1) + (p2 + p3); \
                asm("v_cvt_pk_bf16_f32 %0, %1, %2" : "=v"(U0) : "v"(p0), "v"(p1)); \
                asm("v_cvt_pk_bf16_f32 %0, %1, %2" : "=v"(U1) : "v"(p2), "v"(p3));
                PACK_G(0, u0_0, u0_1)
                PACK_G(1, u1_0, u1_1)
                PACK_G(2, u2_0, u2_1)
                PACK_G(3, u3_0, u3_1)
#undef PACK_G
            }
            lsum += ps;

            // ---- PV: A-frag via permlane32_swap (zero-LDS P), B=V from LDS ----
#define PV_STEP(T2, A0, A1, B0, B1) \
            { \
                uint a0 = A0, b0 = B0, a1 = A1, b1 = B1; \
                asm volatile("v_permlane32_swap_b32 %0, %1" : "+v"(b0), "+v"(a0)); \
                asm volatile("v_permlane32_swap_b32 %0, %1" : "+v"(b1), "+v"(a1)); \
                uint4 fu = make_uint4(a0, a1, b0, b1); \
                short8 pf = *(short8*)&fu; \
                __builtin_amdgcn_s_setprio(1); \
                _Pragma("unroll") \
                for (int dt = 0; dt < 2; dt++) { \
                    int row = dt * 32 + c; \
                    short8 vf = *(const short8*)&vB[row * 128 + \
                                 (((s * 4 + T2 * 2 + h) ^ (row & 7)) << 3)]; \
                    oacc[dt] = __builtin_amdgcn_mfma_f32_32x32x16_bf16( \
                        pf, vf, oacc[dt], 0, 0, 0); \
                } \
                __builtin_amdgcn_s_setprio(0); \
            }
            PV_STEP(0, u0_0, u0_1, u1_0, u1_1)
            PV_STEP(1, u2_0, u2_1, u3_0, u3_1)
#undef PV_STEP
        }
    }
#undef STAGE

    // ---- epilogue: q = c for every value this lane holds -> lane-local 1/l ----
    lsum += __shfl_xor(lsum, 32);
    float rl = 1.f / lsum;
    #pragma unroll
    for (int dt = 0; dt < 2; dt++)
        #pragma unroll
        for (int g = 0; g < 4; g++) {
            float o0 = oacc[dt][4 * g + 0] * rl;
            float o1 = oacc[dt][4 * g + 1] * rl;
            float o2 = oacc[dt][4 * g + 2] * rl;
            float o3 = oacc[dt][4 * g + 3] * rl;
            uint p0, p1;
            asm("v_cvt_pk_bf16_f32 %0, %1, %2" : "=v"(p0) : "v"(o0), "v"(o1));
            asm("v_cvt_pk_bf16_f32 %0, %1, %2" : "=v"(p1) : "v"(o2), "v"(o3));
            int ch = hh * 64 + dt * 32 + 8 * g + 4 * h;
            *(uint2*)&aout[((size_t)bi * N_TOK + qw + c) * 512 + ch] = make_uint2(p0, p1);
        }
}

extern "C" void kernel_launch(void* const* d_in, const int* in_sizes, int n_in,
                              void* d_out, int out_size, void* d_ws, size_t ws_size,
                              hipStream_t stream) {
    const float* x    = (const float*)d_in[0];
    const float* Wqkv = (const float*)d_in[1];
    const float* Wout = (const float*)d_in[2];
    const float* bout = (const float*)d_in[3];
    const float* g1   = (const float*)d_in[4];
    const float* be1  = (const float*)d_in[5];
    const float* m1   = (const float*)d_in[6];
    const float* v1   = (const float*)d_in[7];
    const float* Wffn = (const float*)d_in[8];
    const float* g2   = (const float*)d_in[9];
    const float* be2  = (const float*)d_in[10];
    const float* m2   = (const float*)d_in[11];
    const float* v2   = (const float*)d_in[12];

    char* ws = (char*)d_ws;
    ushort* wqB  = (ushort*)(ws + 0);          // 1.5 MB
    ushort* woB  = (ushort*)(ws + 1572864);    // 0.5 MB
    ushort* wfB  = (ushort*)(ws + 2097152);    // 0.5 MB
    ushort* xt   = (ushort*)(ws + 2621440);    // 8 MB   [b][2048][512] bf16
    ushort* qtp  = (ushort*)(ws + 11010048);   // 16 MB  [b][2048][1024] bf16
    ushort* vcp  = (ushort*)(ws + 27787264);   // 8 MB   [b][512][2048] bf16
    ushort* aout = (ushort*)(ws + 36175872);   // 8 MB   [b][2048][512] bf16
    ushort* attB = (ushort*)(ws + 27787264);   // 8 MB   reuse vcp (dead after attn)

    dim3 blk(256);
    prep<<<2304, blk, 0, stream>>>(Wqkv, wqB, Wout, woB, Wffn, wfB, x, xt);
    bgemm<0, 128, 128><<<dim3(768), blk, 0, stream>>>(
        wqB, xt, 1536, qtp, vcp, nullptr, nullptr,
        nullptr, nullptr, nullptr, nullptr, nullptr, nullptr);
    attn_mfma<<<dim3(256), dim3(512), 0, stream>>>(qtp, vcp, aout);
    bgemm<1, 64, 128><<<dim3(512), blk, 0, stream>>>(
        woB, aout, 512, nullptr, nullptr, nullptr, attB,
        bout, g1, be1, m1, v1, xt);
    bgemm<2, 64, 128><<<dim3(512), blk, 0, stream>>>(
        wfB, attB, 512, nullptr, nullptr, (float*)d_out, nullptr,
        nullptr, g2, be2, m2, v2, attB);
}